// Round 9
// baseline (60.355 us; speedup 1.0000x reference)
//
#include <hip/hip_runtime.h>

typedef __attribute__((ext_vector_type(8))) short short8;
typedef __attribute__((ext_vector_type(4))) float f32x4;

#define B_SZ  16
#define NPTS  4096
#define MBLK  256                  // 4 waves
#define PRB   256                  // pred rows per block (64 per wave, 4 frags)
#define NCH   (NPTS / PRB)         // 16 chunks per (dir,b)
#define STGT  1024                 // targets staged per LDS stage
#define STILE (STGT / 16)          // 64 B-tiles per stage
#define NSTG  (NPTS / STGT)        // 4 stages
#define TOT   (2 * B_SZ * NPTS)    // 131072
#define BLK   256

// float -> bf16 (RNE) and back, raw ushort bit patterns
__device__ __forceinline__ unsigned short f2bf(float f) {
    unsigned u = __float_as_uint(f);
    return (unsigned short)((u + 0x7FFFu + ((u >> 16) & 1u)) >> 16);
}
__device__ __forceinline__ float bf2f(unsigned short s) {
    return __uint_as_float(((unsigned)s) << 16);
}
// -2 * bf16 value (exact: sign/exponent only)
__device__ __forceinline__ short n2(unsigned short s) {
    return (short)f2bf(-2.0f * bf2f(s));
}

// ---------------------------------------------------------------------------
// Split-precision chamfer via v_mfma_f32_16x16x32_bf16.
// d = -2(ph+pl)·(th+tl) + (p2h+p2l) + (t2h+t2l)   (FULL product, K slots 0-15)
//  s0-2 : -2ph{x,y,z} · th{x,y,z}      s3-5 : -2pl · th
//  s6-8 : -2ph · tl                    s9-11: -2pl · tl
//  s12,13: p2h,p2l (·1)                s14,15: 1·(t2h,t2l)     s16-31: 0
// Slot->k permutations cancel (A and B share the k-map); row/col permutations
// cancel in min+mean; the ONLY live layout assumption (C/D grouping for the
// row-min) is verified at runtime by a marker-MFMA probe, with a
// label-indexed LDS atomicMin fallback that is correct under ANY bijection.
// ---------------------------------------------------------------------------
__global__ __launch_bounds__(MBLK, 2) void chamfer_mfma(
    const float* __restrict__ pred, const float* __restrict__ target,
    float* __restrict__ ws)
{
    __shared__ short8 sB[STILE * 64];   // 64 KB pre-packed B fragments
    __shared__ unsigned ldsMin[MBLK];   // fallback label-scatter reduce

    const int dir = blockIdx.y;
    const float* own = dir ? target : pred;
    const float* opp = dir ? pred : target;

    const int b     = blockIdx.x >> 4;
    const int chunk = blockIdx.x & (NCH - 1);
    const int tid   = threadIdx.x;
    const int lane  = tid & 63;
    const int w     = tid >> 6;
    const int c16   = lane & 15;     // assumed col / A-row within tile
    const int g     = lane >> 4;     // assumed k-quarter (slots 8g..8g+7)
    const short ONE = (short)0x3F80; // bf16(1.0)

    // ---- A fragments: 4 x 16 own rows per wave ----
    short8 af[4];
    #pragma unroll
    for (int f = 0; f < 4; ++f) {
        short8 v = {0,0,0,0,0,0,0,0};
        if (g < 2) {
            const float* pp = own +
                ((size_t)b*NPTS + chunk*PRB + w*64 + f*16 + c16)*3;
            float x = pp[0], y = pp[1], z = pp[2];
            unsigned short phx=f2bf(x), phy=f2bf(y), phz=f2bf(z);
            unsigned short plx=f2bf(x-bf2f(phx)), ply=f2bf(y-bf2f(phy)),
                           plz=f2bf(z-bf2f(phz));
            if (g == 0) {
                v[0]=n2(phx); v[1]=n2(phy); v[2]=n2(phz);
                v[3]=n2(plx); v[4]=n2(ply); v[5]=n2(plz);
                v[6]=n2(phx); v[7]=n2(phy);
            } else {
                float p2 = fmaf(z,z,fmaf(y,y,x*x));
                unsigned short p2h=f2bf(p2), p2l=f2bf(p2-bf2f(p2h));
                v[0]=n2(phz); v[1]=n2(plx); v[2]=n2(ply); v[3]=n2(plz);
                v[4]=(short)p2h; v[5]=(short)p2l; v[6]=ONE; v[7]=ONE;
            }
        }
        af[f] = v;
    }

    // ---- layout probe: D(lane,reg) = true row label under ANY layout ----
    const f32x4 zc = {0.f, 0.f, 0.f, 0.f};
    short8 mA = {0,0,0,0,0,0,0,0}, mB = {0,0,0,0,0,0,0,0};
    if (g == 0) { mA[0] = (short)f2bf((float)c16); mB[0] = ONE; }
    f32x4 pr = __builtin_amdgcn_mfma_f32_16x16x32_bf16(mA, mB, zc, 0, 0, 0);
    int lab[4];
    #pragma unroll
    for (int r = 0; r < 4; ++r) lab[r] = ((int)(pr[r] + 0.5f)) & 15;
    const bool fast = __all(lab[0] == g*4+0 && lab[1] == g*4+1 &&
                            lab[2] == g*4+2 && lab[3] == g*4+3) != 0;

    // ---- scan all 4096 targets in 4 staged passes ----
    f32x4 rmin[4];
    #pragma unroll
    for (int f = 0; f < 4; ++f) {
        rmin[f][0]=1e30f; rmin[f][1]=1e30f; rmin[f][2]=1e30f; rmin[f][3]=1e30f;
    }

    const float* oppB = opp + (size_t)b * NPTS * 3;

    for (int s = 0; s < NSTG; ++s) {
        __syncthreads();   // previous stage's compute done
        #pragma unroll
        for (int i = 0; i < (STILE*64)/MBLK; ++i) {   // 16 entries/thread
            int e  = i * MBLK + tid;
            int t  = e >> 6, l2 = e & 63;
            int cc = l2 & 15, gg = l2 >> 4;
            short8 v = {0,0,0,0,0,0,0,0};
            if (gg < 2) {
                const float* o = oppB + (size_t)(s*STGT + t*16 + cc)*3;
                float tx=o[0], ty=o[1], tz=o[2];
                unsigned short hx=f2bf(tx), hy=f2bf(ty), hz=f2bf(tz);
                unsigned short lx=f2bf(tx-bf2f(hx)), ly=f2bf(ty-bf2f(hy)),
                               lz=f2bf(tz-bf2f(hz));
                if (gg == 0) {
                    v[0]=(short)hx; v[1]=(short)hy; v[2]=(short)hz;
                    v[3]=(short)hx; v[4]=(short)hy; v[5]=(short)hz;
                    v[6]=(short)lx; v[7]=(short)ly;
                } else {
                    float t2 = fmaf(tz,tz,fmaf(ty,ty,tx*tx));
                    unsigned short t2h=f2bf(t2), t2l=f2bf(t2-bf2f(t2h));
                    v[0]=(short)lz; v[1]=(short)lx; v[2]=(short)ly;
                    v[3]=(short)lz; v[4]=ONE; v[5]=ONE;
                    v[6]=(short)t2h; v[7]=(short)t2l;
                }
            }
            sB[e] = v;   // contiguous 16B/thread
        }
        __syncthreads();

        for (int t = 0; t < STILE; t += 2) {
            short8 b0 = sB[t*64 + lane];
            short8 b1 = sB[t*64 + 64 + lane];
            #pragma unroll
            for (int f = 0; f < 4; ++f) {
                f32x4 a0 = __builtin_amdgcn_mfma_f32_16x16x32_bf16(af[f], b0, zc, 0,0,0);
                f32x4 a1 = __builtin_amdgcn_mfma_f32_16x16x32_bf16(af[f], b1, zc, 0,0,0);
                #pragma unroll
                for (int r = 0; r < 4; ++r)
                    rmin[f][r] = fminf(fminf(a0[r], a1[r]), rmin[f][r]);
            }
        }
    }

    // ---- epilogue: per-row min over the 16 col-slots, write by LABEL ----
    float* wsblk = ws + ((size_t)dir * B_SZ + b) * NPTS + chunk * PRB;
    if (fast) {
        // verified layout: lanes sharing (lane>>4) hold the same rows
        #pragma unroll
        for (int f = 0; f < 4; ++f) {
            #pragma unroll
            for (int r = 0; r < 4; ++r) {
                float v = rmin[f][r];
                v = fminf(v, __shfl_xor(v, 1, 64));
                v = fminf(v, __shfl_xor(v, 2, 64));
                v = fminf(v, __shfl_xor(v, 4, 64));
                v = fminf(v, __shfl_xor(v, 8, 64));
                if (c16 == 0) wsblk[w*64 + f*16 + lab[r]] = v;
            }
        }
    } else {
        // layout-agnostic: scatter-min by probed label (order-preserving uint)
        ldsMin[tid] = 0x7F7F7F7Fu;
        __syncthreads();
        #pragma unroll
        for (int f = 0; f < 4; ++f)
            #pragma unroll
            for (int r = 0; r < 4; ++r)
                atomicMin(&ldsMin[w*64 + f*16 + lab[r]],
                          __float_as_uint(fmaxf(rmin[f][r], 0.0f)));
        __syncthreads();
        wsblk[tid] = __uint_as_float(ldsMin[tid]);
    }
}

// ---------------- combine kernel: mean-reduce the per-point mins -------------
__global__ __launch_bounds__(BLK) void chamfer_combine(
    const float* __restrict__ ws, float* __restrict__ out)
{
    const int idx = blockIdx.x * BLK + threadIdx.x;   // 0 .. TOT-1
    float v = ws[idx];

    for (int off = 32; off > 0; off >>= 1)
        v += __shfl_down(v, off, 64);

    __shared__ float red[4];
    const int tid = threadIdx.x;
    if ((tid & 63) == 0) red[tid >> 6] = v;
    __syncthreads();
    if (tid == 0) {
        float s = (red[0] + red[1]) + (red[2] + red[3]);
        atomicAdd(out, s * (1.0f / ((float)B_SZ * (float)NPTS)));
    }
}

// ---------------- fallback (round-1 kernel) if ws too small ------------------
__global__ __launch_bounds__(BLK) void chamfer_kernel(
    const float* __restrict__ pred, const float* __restrict__ target,
    float* __restrict__ out)
{
    __shared__ float4 sOpp[NPTS];

    const int dir = blockIdx.y;
    const float* own = (dir == 0) ? pred : target;
    const float* opp = (dir == 0) ? target : pred;

    const int b     = blockIdx.x >> 4;
    const int chunk = blockIdx.x & 15;
    const int tid   = threadIdx.x;

    const float* oppB = opp + (size_t)b * NPTS * 3;
    for (int j = tid; j < NPTS; j += BLK) {
        float x = oppB[3 * j + 0];
        float y = oppB[3 * j + 1];
        float z = oppB[3 * j + 2];
        sOpp[j] = make_float4(-2.0f * x, -2.0f * y, -2.0f * z,
                              fmaf(z, z, fmaf(y, y, x * x)));
    }
    __syncthreads();

    const int i = chunk * BLK + tid;
    const float* op = own + ((size_t)b * NPTS + i) * 3;
    const float px = op[0], py = op[1], pz = op[2];
    const float p2 = fmaf(pz, pz, fmaf(py, py, px * px));

    float m0 = 1e30f, m1 = 1e30f, m2 = 1e30f, m3 = 1e30f;
    for (int j = 0; j < NPTS; j += 8) {
        float4 t0 = sOpp[j + 0];
        float4 t1 = sOpp[j + 1];
        float4 t2 = sOpp[j + 2];
        float4 t3 = sOpp[j + 3];
        float4 t4 = sOpp[j + 4];
        float4 t5 = sOpp[j + 5];
        float4 t6 = sOpp[j + 6];
        float4 t7 = sOpp[j + 7];
        m0 = fminf(m0, fmaf(t0.x, px, fmaf(t0.y, py, fmaf(t0.z, pz, t0.w))));
        m1 = fminf(m1, fmaf(t1.x, px, fmaf(t1.y, py, fmaf(t1.z, pz, t1.w))));
        m2 = fminf(m2, fmaf(t2.x, px, fmaf(t2.y, py, fmaf(t2.z, pz, t2.w))));
        m3 = fminf(m3, fmaf(t3.x, px, fmaf(t3.y, py, fmaf(t3.z, pz, t3.w))));
        m0 = fminf(m0, fmaf(t4.x, px, fmaf(t4.y, py, fmaf(t4.z, pz, t4.w))));
        m1 = fminf(m1, fmaf(t5.x, px, fmaf(t5.y, py, fmaf(t5.z, pz, t5.w))));
        m2 = fminf(m2, fmaf(t6.x, px, fmaf(t6.y, py, fmaf(t6.z, pz, t6.w))));
        m3 = fminf(m3, fmaf(t7.x, px, fmaf(t7.y, py, fmaf(t7.z, pz, t7.w))));
    }
    float v = fminf(fminf(m0, m1), fminf(m2, m3)) + p2;

    for (int off = 32; off > 0; off >>= 1)
        v += __shfl_down(v, off, 64);

    __syncthreads();
    float* red = (float*)sOpp;
    if ((tid & 63) == 0) red[tid >> 6] = v;
    __syncthreads();
    if (tid == 0) {
        float s = (red[0] + red[1]) + (red[2] + red[3]);
        atomicAdd(out, s * (1.0f / ((float)B_SZ * (float)NPTS)));
    }
}

extern "C" void kernel_launch(void* const* d_in, const int* in_sizes, int n_in,
                              void* d_out, int out_size, void* d_ws, size_t ws_size,
                              hipStream_t stream) {
    const float* pred   = (const float*)d_in[0];
    const float* target = (const float*)d_in[1];
    float* out = (float*)d_out;

    hipMemsetAsync(out, 0, sizeof(float), stream);

    const size_t ws_needed = (size_t)TOT * sizeof(float);  // 512 KB
    if (ws_size >= ws_needed) {
        float* ws = (float*)d_ws;
        dim3 grid1(B_SZ * NCH, 2);                 // 256 x 2 = 512 blocks
        chamfer_mfma<<<grid1, MBLK, 0, stream>>>(pred, target, ws);
        chamfer_combine<<<TOT / BLK, BLK, 0, stream>>>(ws, out);
    } else {
        dim3 grid(B_SZ * (NPTS / BLK), 2);
        chamfer_kernel<<<grid, BLK, 0, stream>>>(pred, target, out);
    }
}

// Round 11
// 53.748 us; speedup vs baseline: 1.1229x; 1.1229x over previous
//
#include <hip/hip_runtime.h>

typedef __attribute__((ext_vector_type(8))) short short8;
typedef __attribute__((ext_vector_type(4))) float f32x4;

#define B_SZ  16
#define NPTS  4096
#define MBLK  256                  // 4 waves
#define PRB   256                  // pred rows per block (64/wave, 4 frags)
#define NCH   (NPTS / PRB)         // 16 chunks per (dir,b)
#define NHALF 2                    // target-halves per (dir,b,chunk)
#define TPB_T (NPTS / NHALF)       // 2048 targets scanned per block
#define STGT  512                  // targets staged per LDS stage
#define STILE (STGT / 16)          // 32 B-tiles per stage
#define NSTG  (TPB_T / STGT)       // 4 stages
#define TOT   (2 * B_SZ * NPTS)    // 131072
#define BLK   256

// float -> bf16 (RNE) and back, raw ushort bit patterns
__device__ __forceinline__ unsigned short f2bf(float f) {
    unsigned u = __float_as_uint(f);
    return (unsigned short)((u + 0x7FFFu + ((u >> 16) & 1u)) >> 16);
}
__device__ __forceinline__ float bf2f(unsigned short s) {
    return __uint_as_float(((unsigned)s) << 16);
}
// -2 * bf16 value (exact: sign/exponent only)
__device__ __forceinline__ short n2(unsigned short s) {
    return (short)f2bf(-2.0f * bf2f(s));
}

// ---------------------------------------------------------------------------
// R9-proven split-precision chamfer via v_mfma_f32_16x16x32_bf16 (absmax 0.0
// at R9). THIS ROUND CHANGES ONLY THE WORK DECOMPOSITION: each block scans a
// HALF of the target set through a 32 KB LDS stage -> 1024 blocks = 4
// blocks/CU = 4 waves/SIMD (R9 was 2). Staging loop, slot algebra, probe and
// epilogue are R9 verbatim; partial mins per half go to ws[half], combine
// kernel min-merges (R2-proven pattern).
// ---------------------------------------------------------------------------
__global__ __launch_bounds__(MBLK, 2) void chamfer_mfma(
    const float* __restrict__ pred, const float* __restrict__ target,
    float* __restrict__ ws)
{
    __shared__ short8 sB[STILE * 64];   // 32 KB pre-packed B fragments
    __shared__ unsigned ldsMin[MBLK];   // fallback label-scatter reduce

    const int dir = blockIdx.y;
    const float* own = dir ? target : pred;
    const float* opp = dir ? pred : target;

    const int bx    = blockIdx.x;           // [0, 512)
    const int b     = bx >> 5;              // 32 blocks per batch
    const int chunk = (bx >> 1) & (NCH - 1);
    const int half  = bx & 1;
    const int tid   = threadIdx.x;
    const int lane  = tid & 63;
    const int w     = tid >> 6;
    const int c16   = lane & 15;     // col / A-row within tile
    const int g     = lane >> 4;     // k-quarter (slots 8g..8g+7)
    const short ONE = (short)0x3F80; // bf16(1.0)

    // ---- A fragments: 4 x 16 own rows per wave ----
    short8 af[4];
    #pragma unroll
    for (int f = 0; f < 4; ++f) {
        short8 v = {0,0,0,0,0,0,0,0};
        if (g < 2) {
            const float* pp = own +
                ((size_t)b*NPTS + chunk*PRB + w*64 + f*16 + c16)*3;
            float x = pp[0], y = pp[1], z = pp[2];
            unsigned short phx=f2bf(x), phy=f2bf(y), phz=f2bf(z);
            unsigned short plx=f2bf(x-bf2f(phx)), ply=f2bf(y-bf2f(phy)),
                           plz=f2bf(z-bf2f(phz));
            if (g == 0) {
                v[0]=n2(phx); v[1]=n2(phy); v[2]=n2(phz);
                v[3]=n2(plx); v[4]=n2(ply); v[5]=n2(plz);
                v[6]=n2(phx); v[7]=n2(phy);
            } else {
                float p2 = fmaf(z,z,fmaf(y,y,x*x));
                unsigned short p2h=f2bf(p2), p2l=f2bf(p2-bf2f(p2h));
                v[0]=n2(phz); v[1]=n2(plx); v[2]=n2(ply); v[3]=n2(plz);
                v[4]=(short)p2h; v[5]=(short)p2l; v[6]=ONE; v[7]=ONE;
            }
        }
        af[f] = v;
    }

    // ---- layout probe: D(lane,reg) = true row label under ANY layout ----
    const f32x4 zc = {0.f, 0.f, 0.f, 0.f};
    short8 mA = {0,0,0,0,0,0,0,0}, mB = {0,0,0,0,0,0,0,0};
    if (g == 0) { mA[0] = (short)f2bf((float)c16); mB[0] = ONE; }
    f32x4 pr = __builtin_amdgcn_mfma_f32_16x16x32_bf16(mA, mB, zc, 0, 0, 0);
    int lab[4];
    #pragma unroll
    for (int r = 0; r < 4; ++r) lab[r] = ((int)(pr[r] + 0.5f)) & 15;
    const bool fast = __all(lab[0] == g*4+0 && lab[1] == g*4+1 &&
                            lab[2] == g*4+2 && lab[3] == g*4+3) != 0;

    // ---- scan this block's 2048 targets in 4 staged passes ----
    f32x4 rmin[4];
    #pragma unroll
    for (int f = 0; f < 4; ++f) {
        rmin[f][0]=1e30f; rmin[f][1]=1e30f; rmin[f][2]=1e30f; rmin[f][3]=1e30f;
    }

    const float* oppB = opp + ((size_t)b * NPTS + half * TPB_T) * 3;

    for (int s = 0; s < NSTG; ++s) {
        __syncthreads();   // previous stage's compute done
        #pragma unroll
        for (int i = 0; i < (STILE*64)/MBLK; ++i) {   // 8 entries/thread
            int e  = i * MBLK + tid;
            int t  = e >> 6, l2 = e & 63;
            int cc = l2 & 15, gg = l2 >> 4;
            short8 v = {0,0,0,0,0,0,0,0};
            if (gg < 2) {
                const float* o = oppB + (size_t)(s*STGT + t*16 + cc)*3;
                float tx=o[0], ty=o[1], tz=o[2];
                unsigned short hx=f2bf(tx), hy=f2bf(ty), hz=f2bf(tz);
                unsigned short lx=f2bf(tx-bf2f(hx)), ly=f2bf(ty-bf2f(hy)),
                               lz=f2bf(tz-bf2f(hz));
                if (gg == 0) {
                    v[0]=(short)hx; v[1]=(short)hy; v[2]=(short)hz;
                    v[3]=(short)hx; v[4]=(short)hy; v[5]=(short)hz;
                    v[6]=(short)lx; v[7]=(short)ly;
                } else {
                    float t2 = fmaf(tz,tz,fmaf(ty,ty,tx*tx));
                    unsigned short t2h=f2bf(t2), t2l=f2bf(t2-bf2f(t2h));
                    v[0]=(short)lz; v[1]=(short)lx; v[2]=(short)ly;
                    v[3]=(short)lz; v[4]=ONE; v[5]=ONE;
                    v[6]=(short)t2h; v[7]=(short)t2l;
                }
            }
            sB[e] = v;   // contiguous 16B/thread
        }
        __syncthreads();

        for (int t = 0; t < STILE; t += 2) {
            short8 b0 = sB[t*64 + lane];
            short8 b1 = sB[t*64 + 64 + lane];
            #pragma unroll
            for (int f = 0; f < 4; ++f) {
                f32x4 a0 = __builtin_amdgcn_mfma_f32_16x16x32_bf16(af[f], b0, zc, 0,0,0);
                f32x4 a1 = __builtin_amdgcn_mfma_f32_16x16x32_bf16(af[f], b1, zc, 0,0,0);
                #pragma unroll
                for (int r = 0; r < 4; ++r)
                    rmin[f][r] = fminf(fminf(a0[r], a1[r]), rmin[f][r]);
            }
        }
    }

    // ---- epilogue (R9 verbatim): per-row min over 16 col-slots, by LABEL ---
    float* wsblk = ws + (size_t)half * TOT
                      + ((size_t)dir * B_SZ + b) * NPTS + chunk * PRB;
    if (fast) {
        #pragma unroll
        for (int f = 0; f < 4; ++f) {
            #pragma unroll
            for (int r = 0; r < 4; ++r) {
                float v = rmin[f][r];
                v = fminf(v, __shfl_xor(v, 1, 64));
                v = fminf(v, __shfl_xor(v, 2, 64));
                v = fminf(v, __shfl_xor(v, 4, 64));
                v = fminf(v, __shfl_xor(v, 8, 64));
                if (c16 == 0) wsblk[w*64 + f*16 + lab[r]] = v;
            }
        }
    } else {
        ldsMin[tid] = 0x7F7F7F7Fu;
        __syncthreads();
        #pragma unroll
        for (int f = 0; f < 4; ++f)
            #pragma unroll
            for (int r = 0; r < 4; ++r)
                atomicMin(&ldsMin[w*64 + f*16 + lab[r]],
                          __float_as_uint(fmaxf(rmin[f][r], 0.0f)));
        __syncthreads();
        wsblk[tid] = __uint_as_float(ldsMin[tid]);
    }
}

// -------- combine kernel: min over the 2 halves, then mean-reduce -----------
__global__ __launch_bounds__(BLK) void chamfer_combine(
    const float* __restrict__ ws, float* __restrict__ out)
{
    const int idx = blockIdx.x * BLK + threadIdx.x;   // 0 .. TOT-1
    float v = fminf(ws[idx], ws[TOT + idx]);

    for (int off = 32; off > 0; off >>= 1)
        v += __shfl_down(v, off, 64);

    __shared__ float red[4];
    const int tid = threadIdx.x;
    if ((tid & 63) == 0) red[tid >> 6] = v;
    __syncthreads();
    if (tid == 0) {
        float s = (red[0] + red[1]) + (red[2] + red[3]);
        atomicAdd(out, s * (1.0f / ((float)B_SZ * (float)NPTS)));
    }
}

// ---------------- fallback (round-1 kernel) if ws too small ------------------
__global__ __launch_bounds__(BLK) void chamfer_kernel(
    const float* __restrict__ pred, const float* __restrict__ target,
    float* __restrict__ out)
{
    __shared__ float4 sOpp[NPTS];

    const int dir = blockIdx.y;
    const float* own = (dir == 0) ? pred : target;
    const float* opp = (dir == 0) ? target : pred;

    const int b     = blockIdx.x >> 4;
    const int chunk = blockIdx.x & 15;
    const int tid   = threadIdx.x;

    const float* oppB = opp + (size_t)b * NPTS * 3;
    for (int j = tid; j < NPTS; j += BLK) {
        float x = oppB[3 * j + 0];
        float y = oppB[3 * j + 1];
        float z = oppB[3 * j + 2];
        sOpp[j] = make_float4(-2.0f * x, -2.0f * y, -2.0f * z,
                              fmaf(z, z, fmaf(y, y, x * x)));
    }
    __syncthreads();

    const int i = chunk * BLK + tid;
    const float* op = own + ((size_t)b * NPTS + i) * 3;
    const float px = op[0], py = op[1], pz = op[2];
    const float p2 = fmaf(pz, pz, fmaf(py, py, px * px));

    float m0 = 1e30f, m1 = 1e30f, m2 = 1e30f, m3 = 1e30f;
    for (int j = 0; j < NPTS; j += 8) {
        float4 t0 = sOpp[j + 0];
        float4 t1 = sOpp[j + 1];
        float4 t2 = sOpp[j + 2];
        float4 t3 = sOpp[j + 3];
        float4 t4 = sOpp[j + 4];
        float4 t5 = sOpp[j + 5];
        float4 t6 = sOpp[j + 6];
        float4 t7 = sOpp[j + 7];
        m0 = fminf(m0, fmaf(t0.x, px, fmaf(t0.y, py, fmaf(t0.z, pz, t0.w))));
        m1 = fminf(m1, fmaf(t1.x, px, fmaf(t1.y, py, fmaf(t1.z, pz, t1.w))));
        m2 = fminf(m2, fmaf(t2.x, px, fmaf(t2.y, py, fmaf(t2.z, pz, t2.w))));
        m3 = fminf(m3, fmaf(t3.x, px, fmaf(t3.y, py, fmaf(t3.z, pz, t3.w))));
        m0 = fminf(m0, fmaf(t4.x, px, fmaf(t4.y, py, fmaf(t4.z, pz, t4.w))));
        m1 = fminf(m1, fmaf(t5.x, px, fmaf(t5.y, py, fmaf(t5.z, pz, t5.w))));
        m2 = fminf(m2, fmaf(t6.x, px, fmaf(t6.y, py, fmaf(t6.z, pz, t6.w))));
        m3 = fminf(m3, fmaf(t7.x, px, fmaf(t7.y, py, fmaf(t7.z, pz, t7.w))));
    }
    float v = fminf(fminf(m0, m1), fminf(m2, m3)) + p2;

    for (int off = 32; off > 0; off >>= 1)
        v += __shfl_down(v, off, 64);

    __syncthreads();
    float* red = (float*)sOpp;
    if ((tid & 63) == 0) red[tid >> 6] = v;
    __syncthreads();
    if (tid == 0) {
        float s = (red[0] + red[1]) + (red[2] + red[3]);
        atomicAdd(out, s * (1.0f / ((float)B_SZ * (float)NPTS)));
    }
}

extern "C" void kernel_launch(void* const* d_in, const int* in_sizes, int n_in,
                              void* d_out, int out_size, void* d_ws, size_t ws_size,
                              hipStream_t stream) {
    const float* pred   = (const float*)d_in[0];
    const float* target = (const float*)d_in[1];
    float* out = (float*)d_out;

    hipMemsetAsync(out, 0, sizeof(float), stream);

    const size_t ws_needed = (size_t)NHALF * TOT * sizeof(float);  // 1 MB
    if (ws_size >= ws_needed) {
        float* ws = (float*)d_ws;
        dim3 grid1(B_SZ * NCH * NHALF, 2);         // 512 x 2 = 1024 blocks
        chamfer_mfma<<<grid1, MBLK, 0, stream>>>(pred, target, ws);
        chamfer_combine<<<TOT / BLK, BLK, 0, stream>>>(ws, out);
    } else {
        dim3 grid(B_SZ * (NPTS / BLK), 2);
        chamfer_kernel<<<grid, BLK, 0, stream>>>(pred, target, out);
    }
}

// Round 12
// 45.617 us; speedup vs baseline: 1.3231x; 1.1782x over previous
//
#include <hip/hip_runtime.h>

typedef __attribute__((ext_vector_type(8)))  short short8;
typedef __attribute__((ext_vector_type(16))) float f32x16;

#define B_SZ  16
#define NPTS  4096
#define MBLK  256                  // 4 waves
#define PRB   256                  // pred rows per block (64/wave, 2x32 frags)
#define NFR   2                    // 32-row A fragments per wave
#define NCH   (NPTS / PRB)         // 16 chunks per (dir,b)
#define NHALF 2                    // target-halves per (dir,b,chunk)
#define TPB_T (NPTS / NHALF)       // 2048 targets scanned per block
#define STGT  512                  // targets staged per LDS stage
#define STILE (STGT / 32)          // 16 B-tiles (32 cols each) per stage
#define NSTG  (TPB_T / STGT)       // 4 stages
#define TOT   (2 * B_SZ * NPTS)    // 131072
#define BLK   256

// float -> bf16 (RNE) and back, raw ushort bit patterns
__device__ __forceinline__ unsigned short f2bf(float f) {
    unsigned u = __float_as_uint(f);
    return (unsigned short)((u + 0x7FFFu + ((u >> 16) & 1u)) >> 16);
}
__device__ __forceinline__ float bf2f(unsigned short s) {
    return __uint_as_float(((unsigned)s) << 16);
}
// -2 * bf16 value (exact: sign/exponent only)
__device__ __forceinline__ short n2(unsigned short s) {
    return (short)f2bf(-2.0f * bf2f(s));
}

// ---------------------------------------------------------------------------
// R11's proven split-precision chamfer, ONE change: MFMA shape 16x16x32 ->
// 32x32x16. The 16-slot split algebra exactly fills K=16 (no zero padding):
//  s0-2 : -2ph{x,y,z}·th{x,y,z}   s3-5 : -2pl·th   s6-8 : -2ph·tl
//  s9-11: -2pl·tl                 s12,13: p2h,p2l (x1)  s14,15: 1x(t2h,t2l)
// A lane l: row l&31, k-slots 8h..8h+7 (h=l>>5); B same for cols.
// C/D assumed col=lane&31, row=(r&3)+8*(r>>2)+4*h  [m74/m101] — VERIFIED at
// runtime by the marker probe; on mismatch the label-indexed atomicMin
// fallback stays correct under any bijective layout (R9-proven technique).
// ---------------------------------------------------------------------------
__global__ __launch_bounds__(MBLK, 2) void chamfer_mfma(
    const float* __restrict__ pred, const float* __restrict__ target,
    float* __restrict__ ws)
{
    __shared__ short8 sB[STILE * 64];   // 16 KB pre-packed B fragments
    __shared__ unsigned ldsMin[MBLK];   // fallback label-scatter reduce

    const int dir = blockIdx.y;
    const float* own = dir ? target : pred;
    const float* opp = dir ? pred : target;

    const int bx    = blockIdx.x;           // [0, 512)
    const int b     = bx >> 5;              // NCH*NHALF = 32 blocks per batch
    const int chunk = (bx >> 1) & (NCH - 1);
    const int half  = bx & 1;
    const int tid   = threadIdx.x;
    const int lane  = tid & 63;
    const int w     = tid >> 6;
    const int r32   = lane & 31;     // A-row / B-col within tile
    const int h     = lane >> 5;     // k-half (slots 8h..8h+7)
    const short ONE = (short)0x3F80; // bf16(1.0)

    // ---- A fragments: 2 x 32 own rows per wave ----
    short8 af[NFR];
    #pragma unroll
    for (int f = 0; f < NFR; ++f) {
        const float* pp = own +
            ((size_t)b*NPTS + chunk*PRB + w*64 + f*32 + r32)*3;
        float x = pp[0], y = pp[1], z = pp[2];
        unsigned short phx=f2bf(x), phy=f2bf(y), phz=f2bf(z);
        unsigned short plx=f2bf(x-bf2f(phx)), ply=f2bf(y-bf2f(phy)),
                       plz=f2bf(z-bf2f(phz));
        short8 v;
        if (h == 0) {
            v[0]=n2(phx); v[1]=n2(phy); v[2]=n2(phz);
            v[3]=n2(plx); v[4]=n2(ply); v[5]=n2(plz);
            v[6]=n2(phx); v[7]=n2(phy);
        } else {
            float p2 = fmaf(z,z,fmaf(y,y,x*x));
            unsigned short p2h=f2bf(p2), p2l=f2bf(p2-bf2f(p2h));
            v[0]=n2(phz); v[1]=n2(plx); v[2]=n2(ply); v[3]=n2(plz);
            v[4]=(short)p2h; v[5]=(short)p2l; v[6]=ONE; v[7]=ONE;
        }
        af[f] = v;
    }

    // ---- layout probe: D(lane,reg) = true row label under ANY layout ----
    f32x16 zc;
    #pragma unroll
    for (int r = 0; r < 16; ++r) zc[r] = 0.0f;
    short8 mA = {0,0,0,0,0,0,0,0}, mB = {0,0,0,0,0,0,0,0};
    if (h == 0) { mA[0] = (short)f2bf((float)r32); mB[0] = ONE; }
    f32x16 pr = __builtin_amdgcn_mfma_f32_32x32x16_bf16(mA, mB, zc, 0, 0, 0);
    int lab[16];
    bool ok = true;
    #pragma unroll
    for (int r = 0; r < 16; ++r) {
        lab[r] = ((int)(pr[r] + 0.5f)) & 31;
        ok = ok && (lab[r] == ((r & 3) + 8 * (r >> 2) + 4 * h));
    }
    const bool fast = __all(ok) != 0;

    // ---- scan this block's 2048 targets in 4 staged passes ----
    f32x16 rmin[NFR];
    #pragma unroll
    for (int f = 0; f < NFR; ++f)
        #pragma unroll
        for (int r = 0; r < 16; ++r) rmin[f][r] = 1e30f;

    const float* oppB = opp + ((size_t)b * NPTS + half * TPB_T) * 3;

    for (int s = 0; s < NSTG; ++s) {
        __syncthreads();   // previous stage's compute done
        #pragma unroll
        for (int i = 0; i < (STILE*64)/MBLK; ++i) {   // 4 entries/thread
            int e  = i * MBLK + tid;
            int t  = e >> 6, l2 = e & 63;
            int cc = l2 & 31, hh = l2 >> 5;
            const float* o = oppB + (size_t)(s*STGT + t*32 + cc)*3;
            float tx=o[0], ty=o[1], tz=o[2];
            unsigned short hx=f2bf(tx), hy=f2bf(ty), hz=f2bf(tz);
            unsigned short lx=f2bf(tx-bf2f(hx)), ly=f2bf(ty-bf2f(hy)),
                           lz=f2bf(tz-bf2f(hz));
            short8 v;
            if (hh == 0) {
                v[0]=(short)hx; v[1]=(short)hy; v[2]=(short)hz;
                v[3]=(short)hx; v[4]=(short)hy; v[5]=(short)hz;
                v[6]=(short)lx; v[7]=(short)ly;
            } else {
                float t2 = fmaf(tz,tz,fmaf(ty,ty,tx*tx));
                unsigned short t2h=f2bf(t2), t2l=f2bf(t2-bf2f(t2h));
                v[0]=(short)lz; v[1]=(short)lx; v[2]=(short)ly;
                v[3]=(short)lz; v[4]=ONE; v[5]=ONE;
                v[6]=(short)t2h; v[7]=(short)t2l;
            }
            sB[e] = v;   // contiguous 16B/thread
        }
        __syncthreads();

        for (int t = 0; t < STILE; t += 2) {
            short8 b0 = sB[t*64 + lane];
            short8 b1 = sB[t*64 + 64 + lane];
            #pragma unroll
            for (int f = 0; f < NFR; ++f) {
                f32x16 a0 = __builtin_amdgcn_mfma_f32_32x32x16_bf16(af[f], b0, zc, 0,0,0);
                f32x16 a1 = __builtin_amdgcn_mfma_f32_32x32x16_bf16(af[f], b1, zc, 0,0,0);
                #pragma unroll
                for (int r = 0; r < 16; ++r)
                    rmin[f][r] = fminf(fminf(a0[r], a1[r]), rmin[f][r]);
            }
        }
    }

    // ---- epilogue: per-row min over 32 col-slots, write by LABEL ----
    float* wsblk = ws + (size_t)half * TOT
                      + ((size_t)dir * B_SZ + b) * NPTS + chunk * PRB;
    if (fast) {
        #pragma unroll
        for (int f = 0; f < NFR; ++f) {
            #pragma unroll
            for (int r = 0; r < 16; ++r) {
                float v = rmin[f][r];
                v = fminf(v, __shfl_xor(v, 1, 64));
                v = fminf(v, __shfl_xor(v, 2, 64));
                v = fminf(v, __shfl_xor(v, 4, 64));
                v = fminf(v, __shfl_xor(v, 8, 64));
                v = fminf(v, __shfl_xor(v, 16, 64));
                if (r32 == 0)   // lanes 0,32: one writer per row
                    wsblk[w*64 + f*32 + lab[r]] = v;
            }
        }
    } else {
        ldsMin[tid] = 0x7F7F7F7Fu;
        __syncthreads();
        #pragma unroll
        for (int f = 0; f < NFR; ++f)
            #pragma unroll
            for (int r = 0; r < 16; ++r)
                atomicMin(&ldsMin[w*64 + f*32 + lab[r]],
                          __float_as_uint(fmaxf(rmin[f][r], 0.0f)));
        __syncthreads();
        wsblk[tid] = __uint_as_float(ldsMin[tid]);
    }
}

// -------- combine kernel: min over the 2 halves, then mean-reduce -----------
__global__ __launch_bounds__(BLK) void chamfer_combine(
    const float* __restrict__ ws, float* __restrict__ out)
{
    const int idx = blockIdx.x * BLK + threadIdx.x;   // 0 .. TOT-1
    float v = fminf(ws[idx], ws[TOT + idx]);

    for (int off = 32; off > 0; off >>= 1)
        v += __shfl_down(v, off, 64);

    __shared__ float red[4];
    const int tid = threadIdx.x;
    if ((tid & 63) == 0) red[tid >> 6] = v;
    __syncthreads();
    if (tid == 0) {
        float s = (red[0] + red[1]) + (red[2] + red[3]);
        atomicAdd(out, s * (1.0f / ((float)B_SZ * (float)NPTS)));
    }
}

// ---------------- fallback (round-1 kernel) if ws too small ------------------
__global__ __launch_bounds__(BLK) void chamfer_kernel(
    const float* __restrict__ pred, const float* __restrict__ target,
    float* __restrict__ out)
{
    __shared__ float4 sOpp[NPTS];

    const int dir = blockIdx.y;
    const float* own = (dir == 0) ? pred : target;
    const float* opp = (dir == 0) ? target : pred;

    const int b     = blockIdx.x >> 4;
    const int chunk = blockIdx.x & 15;
    const int tid   = threadIdx.x;

    const float* oppB = opp + (size_t)b * NPTS * 3;
    for (int j = tid; j < NPTS; j += BLK) {
        float x = oppB[3 * j + 0];
        float y = oppB[3 * j + 1];
        float z = oppB[3 * j + 2];
        sOpp[j] = make_float4(-2.0f * x, -2.0f * y, -2.0f * z,
                              fmaf(z, z, fmaf(y, y, x * x)));
    }
    __syncthreads();

    const int i = chunk * BLK + tid;
    const float* op = own + ((size_t)b * NPTS + i) * 3;
    const float px = op[0], py = op[1], pz = op[2];
    const float p2 = fmaf(pz, pz, fmaf(py, py, px * px));

    float m0 = 1e30f, m1 = 1e30f, m2 = 1e30f, m3 = 1e30f;
    for (int j = 0; j < NPTS; j += 8) {
        float4 t0 = sOpp[j + 0];
        float4 t1 = sOpp[j + 1];
        float4 t2 = sOpp[j + 2];
        float4 t3 = sOpp[j + 3];
        float4 t4 = sOpp[j + 4];
        float4 t5 = sOpp[j + 5];
        float4 t6 = sOpp[j + 6];
        float4 t7 = sOpp[j + 7];
        m0 = fminf(m0, fmaf(t0.x, px, fmaf(t0.y, py, fmaf(t0.z, pz, t0.w))));
        m1 = fminf(m1, fmaf(t1.x, px, fmaf(t1.y, py, fmaf(t1.z, pz, t1.w))));
        m2 = fminf(m2, fmaf(t2.x, px, fmaf(t2.y, py, fmaf(t2.z, pz, t2.w))));
        m3 = fminf(m3, fmaf(t3.x, px, fmaf(t3.y, py, fmaf(t3.z, pz, t3.w))));
        m0 = fminf(m0, fmaf(t4.x, px, fmaf(t4.y, py, fmaf(t4.z, pz, t4.w))));
        m1 = fminf(m1, fmaf(t5.x, px, fmaf(t5.y, py, fmaf(t5.z, pz, t5.w))));
        m2 = fminf(m2, fmaf(t6.x, px, fmaf(t6.y, py, fmaf(t6.z, pz, t6.w))));
        m3 = fminf(m3, fmaf(t7.x, px, fmaf(t7.y, py, fmaf(t7.z, pz, t7.w))));
    }
    float v = fminf(fminf(m0, m1), fminf(m2, m3)) + p2;

    for (int off = 32; off > 0; off >>= 1)
        v += __shfl_down(v, off, 64);

    __syncthreads();
    float* red = (float*)sOpp;
    if ((tid & 63) == 0) red[tid >> 6] = v;
    __syncthreads();
    if (tid == 0) {
        float s = (red[0] + red[1]) + (red[2] + red[3]);
        atomicAdd(out, s * (1.0f / ((float)B_SZ * (float)NPTS)));
    }
}

extern "C" void kernel_launch(void* const* d_in, const int* in_sizes, int n_in,
                              void* d_out, int out_size, void* d_ws, size_t ws_size,
                              hipStream_t stream) {
    const float* pred   = (const float*)d_in[0];
    const float* target = (const float*)d_in[1];
    float* out = (float*)d_out;

    hipMemsetAsync(out, 0, sizeof(float), stream);

    const size_t ws_needed = (size_t)NHALF * TOT * sizeof(float);  // 1 MB
    if (ws_size >= ws_needed) {
        float* ws = (float*)d_ws;
        dim3 grid1(B_SZ * NCH * NHALF, 2);         // 512 x 2 = 1024 blocks
        chamfer_mfma<<<grid1, MBLK, 0, stream>>>(pred, target, ws);
        chamfer_combine<<<TOT / BLK, BLK, 0, stream>>>(ws, out);
    } else {
        dim3 grid(B_SZ * (NPTS / BLK), 2);
        chamfer_kernel<<<grid, BLK, 0, stream>>>(pred, target, out);
    }
}